// Round 1
// baseline (623.155 us; speedup 1.0000x reference)
//
#include <hip/hip_runtime.h>
#include <math.h>

// Problem constants
#define SB 4
#define SS 2048
#define SD 1024
#define SH 16
#define SHD 64
#define SM (SB * SS) // 8192 rows

using f32x4 = __attribute__((ext_vector_type(4))) float;
using s16x8 = __attribute__((ext_vector_type(8))) short;

__device__ __forceinline__ unsigned short f2bf(float x) {
  unsigned int u = __float_as_uint(x);
  u = (u + 0x7fffu + ((u >> 16) & 1u)) >> 16; // RNE
  return (unsigned short)u;
}

__device__ __forceinline__ void gld_lds16(const unsigned short* g, unsigned short* l) {
  __builtin_amdgcn_global_load_lds(
      (const __attribute__((address_space(1))) unsigned int*)g,
      (__attribute__((address_space(3))) unsigned int*)l, 16, 0, 0);
}

// ---------------- fp32 -> bf16 convert (4 elems/thread) ----------------
__global__ __launch_bounds__(256) void cvt4(const float* __restrict__ in,
                                            unsigned short* __restrict__ out, int n4) {
  int i = blockIdx.x * 256 + threadIdx.x;
  if (i >= n4) return;
  float4 v = ((const float4*)in)[i];
  unsigned long long r = (unsigned long long)f2bf(v.x)
                       | ((unsigned long long)f2bf(v.y) << 16)
                       | ((unsigned long long)f2bf(v.z) << 32)
                       | ((unsigned long long)f2bf(v.w) << 48);
  ((unsigned long long*)out)[i] = r;
}

// ---------------- fused QKV projection GEMM ----------------
// C[m,n] = sum_k X[m,k] * W[n,k] + bias[n]   (torch Linear, W row-major [N,K])
// M=8192, N=1024, K=1024. 128x128 tile, 4 waves (2x2 of 64x64), BK=32.
__global__ __launch_bounds__(256) void gemm_qkv(
    const unsigned short* __restrict__ Xb,
    const unsigned short* __restrict__ Wqb, const unsigned short* __restrict__ Wkb,
    const unsigned short* __restrict__ Wvb,
    const float* __restrict__ bq, const float* __restrict__ bk, const float* __restrict__ bv,
    unsigned short* __restrict__ Qb, unsigned short* __restrict__ Kb,
    unsigned short* __restrict__ Vb) {
  __shared__ unsigned short lA[128 * 32];
  __shared__ unsigned short lB[128 * 32];
  const int z = blockIdx.z;
  const unsigned short* W = (z == 0) ? Wqb : (z == 1) ? Wkb : Wvb;
  const float* bias = (z == 0) ? bq : (z == 1) ? bk : bv;
  unsigned short* C = (z == 0) ? Qb : (z == 1) ? Kb : Vb;

  const int tid = threadIdx.x;
  const int wave = tid >> 6, lane = tid & 63;
  const int quad = lane >> 4, l16 = lane & 15;
  const int tN = blockIdx.x * 128, tM = blockIdx.y * 128;
  const int wr = (wave >> 1) * 64, wc = (wave & 1) * 64;

  f32x4 acc[4][4] = {};

  // staging: chunk c (16B) -> LDS row-major [128][32]: row=c>>2, col8=(c&3)*8
  const int c0 = tid, c1 = 256 + tid;
  const int r0 = c0 >> 2, q0 = (c0 & 3) * 8;
  const int r1 = c1 >> 2, q1 = (c1 & 3) * 8;
  const unsigned short* gA0 = Xb + (size_t)(tM + r0) * SD + q0;
  const unsigned short* gB0 = W  + (size_t)(tN + r0) * SD + q0;
  const unsigned short* gA1 = Xb + (size_t)(tM + r1) * SD + q1;
  const unsigned short* gB1 = W  + (size_t)(tN + r1) * SD + q1;
  unsigned short* lA0 = lA + (wave * 64) * 8;      // wave-uniform LDS bases
  unsigned short* lB0 = lB + (wave * 64) * 8;
  unsigned short* lA1 = lA + (256 + wave * 64) * 8;
  unsigned short* lB1 = lB + (256 + wave * 64) * 8;

  for (int k0 = 0; k0 < SD; k0 += 32) {
    __syncthreads(); // WAR: previous iter's LDS reads done
    gld_lds16(gA0 + k0, lA0);
    gld_lds16(gB0 + k0, lB0);
    gld_lds16(gA1 + k0, lA1);
    gld_lds16(gB1 + k0, lB1);
    __syncthreads(); // drains vmcnt -> LDS valid

    s16x8 af[4], bf[4];
#pragma unroll
    for (int i = 0; i < 4; ++i)
      af[i] = *(const s16x8*)(lA + (wr + i * 16 + l16) * 32 + quad * 8);
#pragma unroll
    for (int i = 0; i < 4; ++i)
      bf[i] = *(const s16x8*)(lB + (wc + i * 16 + l16) * 32 + quad * 8);
#pragma unroll
    for (int mi = 0; mi < 4; ++mi)
#pragma unroll
      for (int ni = 0; ni < 4; ++ni)
        acc[mi][ni] = __builtin_amdgcn_mfma_f32_16x16x32_bf16(af[mi], bf[ni], acc[mi][ni], 0, 0, 0);
  }

  // epilogue: C/D layout col=lane&15, row=quad*4+reg
#pragma unroll
  for (int ni = 0; ni < 4; ++ni) {
    const int gn = tN + wc + ni * 16 + l16;
    const float bb = bias[gn];
#pragma unroll
    for (int mi = 0; mi < 4; ++mi) {
#pragma unroll
      for (int r = 0; r < 4; ++r) {
        const int gm = tM + wr + mi * 16 + quad * 4 + r;
        C[(size_t)gm * SD + gn] = f2bf(acc[mi][ni][r] + bb);
      }
    }
  }
}

// ---------------- V transpose: [B,S,D] -> Vt[B*H*64 + d][S] ----------------
__global__ __launch_bounds__(256) void transpose_v(const unsigned short* __restrict__ Vb,
                                                   unsigned short* __restrict__ Vt) {
  __shared__ unsigned short tv[64][70]; // 140B rows: u32-aligned, odd dword stride
  const int tid = threadIdx.x;
  const int st = blockIdx.x * 64;
  const int bh = blockIdx.y;
  const int b = bh >> 4, h = bh & 15;
#pragma unroll
  for (int i = 0; i < 2; ++i) {
    int idx = i * 256 + tid;
    int sl = idx >> 3, c8 = idx & 7;
    const unsigned short* src = Vb + ((size_t)(b * SS + st + sl)) * SD + h * 64 + c8 * 8;
    uint4 v = *(const uint4*)src;
    unsigned int* d32 = (unsigned int*)&tv[sl][c8 * 8];
    d32[0] = v.x; d32[1] = v.y; d32[2] = v.z; d32[3] = v.w;
  }
  __syncthreads();
#pragma unroll
  for (int i = 0; i < 2; ++i) {
    int idx = i * 256 + tid;
    int dl = idx >> 3, sc = idx & 7;
    unsigned short tmp[8];
#pragma unroll
    for (int j = 0; j < 8; ++j) tmp[j] = tv[sc * 8 + j][dl];
    uint4 v;
    v.x = tmp[0] | ((unsigned)tmp[1] << 16);
    v.y = tmp[2] | ((unsigned)tmp[3] << 16);
    v.z = tmp[4] | ((unsigned)tmp[5] << 16);
    v.w = tmp[6] | ((unsigned)tmp[7] << 16);
    *(uint4*)(Vt + ((size_t)(bh * 64 + dl)) * SS + st + sc * 8) = v;
  }
}

// ---------------- flash attention ----------------
// block = (bh, qtile of 64 q-rows); 4 waves, wave owns 16 q-rows.
// A-op: lane holds A[m=lane&15][k=quad*8+j]; B-op: B[n=lane&15][k=quad*8+j];
// C/D:  col=lane&15, row=quad*4+reg.
__global__ __launch_bounds__(256) void attn(const unsigned short* __restrict__ Qb,
                                            const unsigned short* __restrict__ Kb,
                                            const unsigned short* __restrict__ Vt,
                                            float* __restrict__ out) {
  __shared__ unsigned short pl[4][16 * 72]; // per-wave P tile [16 q-rows][64 keys], stride 72
  const int tid = threadIdx.x;
  const int wave = tid >> 6, lane = tid & 63;
  const int quad = lane >> 4, l16 = lane & 15;
  const int qt = blockIdx.x & 31, bh = blockIdx.x >> 5;
  const int b = bh >> 4, h = bh & 15;
  const int qs = qt * 64 + wave * 16;

  const unsigned short* qp = Qb + ((size_t)(b * SS + qs + l16)) * SD + h * 64 + quad * 8;
  s16x8 aq0 = *(const s16x8*)(qp);
  s16x8 aq1 = *(const s16x8*)(qp + 32);

  const unsigned short* kbp = Kb + ((size_t)b * SS) * SD + h * 64;
  const unsigned short* vbp = Vt + ((size_t)bh * 64) * SS;

  f32x4 ov[4] = {};
  float m_i[4], l_i[4];
#pragma unroll
  for (int r = 0; r < 4; ++r) { m_i[r] = -1e30f; l_i[r] = 0.f; }
  unsigned short* pw = pl[wave];
  const float c2 = 0.125f * 1.44269504088896f; // scale * log2(e)

  for (int kt = 0; kt < 32; ++kt) {
    const int k0 = kt * 64;
    f32x4 s[4] = {};
#pragma unroll
    for (int kk = 0; kk < 2; ++kk) {
      const unsigned short* kp = kbp + ((size_t)(k0 + l16)) * SD + kk * 32 + quad * 8;
      s16x8 aqk = kk ? aq1 : aq0;
#pragma unroll
      for (int nt = 0; nt < 4; ++nt) {
        s16x8 bk = *(const s16x8*)(kp + (size_t)nt * 16 * SD);
        s[nt] = __builtin_amdgcn_mfma_f32_16x16x32_bf16(aqk, bk, s[nt], 0, 0, 0);
      }
    }
    // online softmax over this 64-key tile (scores scaled by 0.125 inside exp2)
    float mx[4], rs[4], al[4];
#pragma unroll
    for (int r = 0; r < 4; ++r)
      mx[r] = fmaxf(fmaxf(s[0][r], s[1][r]), fmaxf(s[2][r], s[3][r]));
#pragma unroll
    for (int off = 1; off < 16; off <<= 1)
#pragma unroll
      for (int r = 0; r < 4; ++r) mx[r] = fmaxf(mx[r], __shfl_xor(mx[r], off));
#pragma unroll
    for (int r = 0; r < 4; ++r) {
      float mn = fmaxf(m_i[r], mx[r]);
      al[r] = exp2f((m_i[r] - mn) * c2);
      m_i[r] = mn;
      rs[r] = 0.f;
    }
#pragma unroll
    for (int nt = 0; nt < 4; ++nt)
#pragma unroll
      for (int r = 0; r < 4; ++r) {
        float p = exp2f((s[nt][r] - m_i[r]) * c2);
        rs[r] += p;
        pw[(quad * 4 + r) * 72 + nt * 16 + l16] = f2bf(p);
      }
#pragma unroll
    for (int off = 1; off < 16; off <<= 1)
#pragma unroll
      for (int r = 0; r < 4; ++r) rs[r] += __shfl_xor(rs[r], off);
#pragma unroll
    for (int r = 0; r < 4; ++r) l_i[r] = l_i[r] * al[r] + rs[r];
#pragma unroll
    for (int f = 0; f < 4; ++f)
#pragma unroll
      for (int r = 0; r < 4; ++r) ov[f][r] *= al[r];

    // P (C-layout) -> A-operand layout via wave-local LDS round-trip
    asm volatile("s_waitcnt lgkmcnt(0)" ::: "memory");
    s16x8 pa0 = *(const s16x8*)(pw + l16 * 72 + quad * 8);
    s16x8 pa1 = *(const s16x8*)(pw + l16 * 72 + 32 + quad * 8);
#pragma unroll
    for (int f = 0; f < 4; ++f) {
      const unsigned short* vp = vbp + ((size_t)(f * 16 + l16)) * SS + k0 + quad * 8;
      s16x8 bv0 = *(const s16x8*)(vp);
      s16x8 bv1 = *(const s16x8*)(vp + 32);
      ov[f] = __builtin_amdgcn_mfma_f32_16x16x32_bf16(pa0, bv0, ov[f], 0, 0, 0);
      ov[f] = __builtin_amdgcn_mfma_f32_16x16x32_bf16(pa1, bv1, ov[f], 0, 0, 0);
    }
  }
  // epilogue: out[b, s, h*64 + d], fp32
#pragma unroll
  for (int r = 0; r < 4; ++r) {
    const float inv = 1.0f / l_i[r];
    const size_t row = (size_t)(b * SS + qs + quad * 4 + r) * SD + h * 64;
#pragma unroll
    for (int f = 0; f < 4; ++f) out[row + f * 16 + l16] = ov[f][r] * inv;
  }
}

extern "C" void kernel_launch(void* const* d_in, const int* in_sizes, int n_in,
                              void* d_out, int out_size, void* d_ws, size_t ws_size,
                              hipStream_t stream) {
  const float* hs = (const float*)d_in[0];
  const float* Wq = (const float*)d_in[1];
  const float* bq = (const float*)d_in[2];
  const float* Wk = (const float*)d_in[3];
  const float* bk = (const float*)d_in[4];
  const float* Wv = (const float*)d_in[5];
  const float* bv = (const float*)d_in[6];
  float* out = (float*)d_out;

  char* ws = (char*)d_ws;
  // workspace layout (bytes): Xb 16M | Wq/Wk/Wv 2M each | Qb/Kb/Vb/Vt 16M each ≈ 86MB
  unsigned short* Xb  = (unsigned short*)(ws);
  unsigned short* Wqb = (unsigned short*)(ws + 16777216);
  unsigned short* Wkb = (unsigned short*)(ws + 16777216 + 2097152);
  unsigned short* Wvb = (unsigned short*)(ws + 16777216 + 2 * 2097152);
  unsigned short* Qb  = (unsigned short*)(ws + 16777216 + 3 * 2097152);
  unsigned short* Kb  = Qb + (size_t)SM * SD;
  unsigned short* Vb  = Kb + (size_t)SM * SD;
  unsigned short* Vt  = Vb + (size_t)SM * SD;

  cvt4<<<dim3(8192), dim3(256), 0, stream>>>(hs, Xb, SM * SD / 4);
  cvt4<<<dim3(1024), dim3(256), 0, stream>>>(Wq, Wqb, SD * SD / 4);
  cvt4<<<dim3(1024), dim3(256), 0, stream>>>(Wk, Wkb, SD * SD / 4);
  cvt4<<<dim3(1024), dim3(256), 0, stream>>>(Wv, Wvb, SD * SD / 4);
  gemm_qkv<<<dim3(SD / 128, SM / 128, 3), dim3(256), 0, stream>>>(
      Xb, Wqb, Wkb, Wvb, bq, bk, bv, Qb, Kb, Vb);
  transpose_v<<<dim3(SS / 64, SB * SH), dim3(256), 0, stream>>>(Vb, Vt);
  attn<<<dim3(SB * SH * (SS / 64)), dim3(256), 0, stream>>>(Qb, Kb, Vt, out);
}